// Round 4
// baseline (536.201 us; speedup 1.0000x reference)
//
#include <hip/hip_runtime.h>
#include <hip/hip_bf16.h>
#include <stdint.h>

typedef unsigned short u16;
typedef __attribute__((ext_vector_type(8))) short bf16x8;
typedef __attribute__((ext_vector_type(4))) float f32x4;

#define HEADS 8
#define DHEAD 128
#define NSEQ 1024
#define BATCH 4
#define DIM 1024
#define ATT_SCALE 0.088388347648318447f  // 1/sqrt(128)

static __device__ __forceinline__ float bf2f(u16 u){
  union { unsigned int i; float f; } c; c.i = ((unsigned int)u) << 16; return c.f;
}
static __device__ __forceinline__ u16 f2bf(float f){
  union { float f; unsigned int i; } c; c.f = f;
  unsigned int x = c.i;
  return (u16)((x + 0x7fffu + ((x >> 16) & 1u)) >> 16);
}

// async global->LDS, 16B per lane, dest = wave-uniform base + lane*16
static __device__ __forceinline__ void gload_lds16(const void* g, void* l){
  __builtin_amdgcn_global_load_lds((__attribute__((address_space(1))) void*)(g),
                                   (__attribute__((address_space(3))) void*)(l),
                                   16, 0, 0);
}

// ---------------- LayerNorm x3 fused: fp32 in, bf16 out ---------------------
// grid (4096, 3): y=0 x->xn (ln), y=1 ref->rn (ln), y=2 cinfo->cn (cln)
__global__ __launch_bounds__(256)
void ln3_kernel(const float* __restrict__ x, const float* __restrict__ ref,
                const float* __restrict__ cinfo,
                const float* __restrict__ ln_w, const float* __restrict__ ln_b,
                const float* __restrict__ cln_w, const float* __restrict__ cln_b,
                u16* __restrict__ xn, u16* __restrict__ rn, u16* __restrict__ cn)
{
  const int z = blockIdx.y;
  const float* src = (z==0) ? x : (z==1) ? ref : cinfo;
  const float* w   = (z==2) ? cln_w : ln_w;
  const float* b   = (z==2) ? cln_b : ln_b;
  u16* out         = (z==0) ? xn : (z==1) ? rn : cn;

  const int row = blockIdx.x;
  const int t = threadIdx.x;
  const float* xr = src + (size_t)row * DIM;
  float4 v4 = *(const float4*)(xr + t*4);
  float v[4] = {v4.x, v4.y, v4.z, v4.w};
  float s = v[0]+v[1]+v[2]+v[3];
  __shared__ float red[256];
  red[t] = s; __syncthreads();
  for (int o=128;o;o>>=1){ if (t<o) red[t]+=red[t+o]; __syncthreads(); }
  const float mean = red[0] * (1.0f/DIM);
  __syncthreads();
  s = 0.f;
#pragma unroll
  for (int i=0;i<4;i++){ float d = v[i]-mean; s += d*d; }
  red[t] = s; __syncthreads();
  for (int o=128;o;o>>=1){ if (t<o) red[t]+=red[t+o]; __syncthreads(); }
  const float rstd = rsqrtf(red[0]*(1.0f/DIM) + 1e-5f);
  float4 w4 = *(const float4*)(w + t*4);
  float4 b4 = *(const float4*)(b + t*4);
  float wv[4] = {w4.x, w4.y, w4.z, w4.w};
  float bv[4] = {b4.x, b4.y, b4.z, b4.w};
  union { uint2 u; u16 s[4]; } ov;
#pragma unroll
  for (int i=0;i<4;i++)
    ov.s[i] = f2bf((v[i]-mean)*rstd*wv[i] + bv[i]);
  *(uint2*)(out + (size_t)row*DIM + t*4) = ov.u;
}

// -------- weight convert+transpose: fp32 [K,1024] -> bf16 [1024,K] ----------
__global__ __launch_bounds__(256)
void wcvt_kernel(const float* __restrict__ Wk, const float* __restrict__ Wv,
                 const float* __restrict__ Wo,
                 u16* __restrict__ WkT, u16* __restrict__ WvT, u16* __restrict__ WoT)
{
  const int z = blockIdx.z;
  const int K = (z==0) ? 3072 : (z==1) ? 2048 : 1024;
  if ((int)blockIdx.x*32 >= K) return;
  const float* W = (z==0) ? Wk : (z==1) ? Wv : Wo;
  u16* WT = (z==0) ? WkT : (z==1) ? WvT : WoT;
  __shared__ float tile[32][33];
  const int k0 = blockIdx.x*32, n0 = blockIdx.y*32;
  const int t = threadIdx.x, tc = t&31, tr = t>>5;
#pragma unroll
  for (int p=0;p<4;p++)
    tile[tr+p*8][tc] = W[(size_t)(k0+tr+p*8)*DIM + n0+tc];
  __syncthreads();
#pragma unroll
  for (int p=0;p<4;p++)
    WT[(size_t)(n0+tr+p*8)*K + k0+tc] = f2bf(tile[tc][tr+p*8]);
}

// ------ 64x64-per-wave reg-blocked GEMM for step 2: NO LDS, NO barriers -----
// grid (8,32,2): block = 128x128 C-tile, 4 INDEPENDENT waves own 64x64 each.
// z=0: cond = [xn|cn|rn](4096x3072) @ WkT^T ; z=1: refv = [xn|rn](4096x2048) @ WvT^T.
// Fragments loaded straight global->VGPR (per-lane addr identical to the old
// staged-LDS layout: lane l of frag f reads row base+f*16+(l&15), k-oct l>>4).
// 4-deep register ping-pong (KT%4==0): at each MFMA phase, 3 tiles (24 loads)
// are in flight -> compiler emits counted s_waitcnt vmcnt(24) automatically.
// 2048 independent latency chains vs the old 512 coupled 4-wave blocks.
// Output: epi3 head-split bf16.
__global__ __launch_bounds__(256, 2)
void gemm64_kernel(const u16* __restrict__ xn, const u16* __restrict__ cn,
                   const u16* __restrict__ rn,
                   const u16* __restrict__ WkT, const u16* __restrict__ WvT,
                   u16* __restrict__ cond, u16* __restrict__ refv)
{
  const int t = threadIdx.x;
  const int wave = t>>6, lane = t&63;
  const int side = blockIdx.z;                 // 0: cond K=3072; 1: refv K=2048
  const int K    = side ? 2048 : 3072;
  const int KT   = K >> 5;
  const u16* B   = side ? WvT : WkT;
  u16* Cp        = side ? refv : cond;
  const int m0 = blockIdx.y*128 + (wave>>1)*64;
  const int n0 = blockIdx.x*128 + (wave&1)*64;
  const int lm = lane&15, q = lane>>4;

  const f32x4 zero4 = {0.f,0.f,0.f,0.f};
  f32x4 acc[4][4];
#pragma unroll
  for (int i=0;i<4;i++)
#pragma unroll
    for (int j=0;j<4;j++) acc[i][j] = zero4;

  auto loadA = [&](int kt, bf16x8* a){
    const int kg = kt<<5;
    const int seg = kg>>10;
    const int ka = (kg&1023) + q*8;
    const u16* Ap = side ? (seg==0 ? xn : rn)
                         : (seg==0 ? xn : (seg==1 ? cn : rn));
#pragma unroll
    for (int f=0; f<4; ++f)
      a[f] = *(const bf16x8*)(Ap + (size_t)(m0 + f*16 + lm)*DIM + ka);
  };
  auto loadB = [&](int kt, bf16x8* b){
    const int kb = (kt<<5) + q*8;
#pragma unroll
    for (int f=0; f<4; ++f)
      b[f] = *(const bf16x8*)(B + (size_t)(n0 + f*16 + lm)*(size_t)K + kb);
  };

#define MMA4(aa, bb)                                                            \
  do {                                                                          \
    _Pragma("unroll")                                                           \
    for (int fm=0; fm<4; ++fm)                                                  \
      _Pragma("unroll")                                                         \
      for (int fn=0; fn<4; ++fn)                                                \
        acc[fm][fn] = __builtin_amdgcn_mfma_f32_16x16x32_bf16(aa[fm], bb[fn],   \
                                                              acc[fm][fn], 0,0,0);\
  } while (0)

  bf16x8 aP[4], bP[4], aQ[4], bQ[4], aR[4], bR[4], aS[4], bS[4];
  loadA(0, aP); loadB(0, bP);
  loadA(1, aQ); loadB(1, bQ);
  loadA(2, aR); loadB(2, bR);
  loadA(3, aS); loadB(3, bS);

  for (int kt=0; kt<KT; kt+=4){            // KT = 96 or 64, both %4==0
    MMA4(aP, bP);
    if (kt+4 < KT){ loadA(kt+4, aP); loadB(kt+4, bP); }
    MMA4(aQ, bQ);
    if (kt+5 < KT){ loadA(kt+5, aQ); loadB(kt+5, bQ); }
    MMA4(aR, bR);
    if (kt+6 < KT){ loadA(kt+6, aR); loadB(kt+6, bR); }
    MMA4(aS, bS);
    if (kt+7 < KT){ loadA(kt+7, aS); loadB(kt+7, bS); }
  }
#undef MMA4

  // epilogue: epi3 head-split bf16
#pragma unroll
  for (int fm=0; fm<4; ++fm){
#pragma unroll
    for (int fn=0; fn<4; ++fn){
#pragma unroll
      for (int r=0; r<4; ++r){
        const int m = m0 + fm*16 + q*4 + r;
        const int n = n0 + fn*16 + lm;
        Cp[(size_t)(((m>>10)*HEADS + (n>>7))*NSEQ + (m&1023))*DHEAD + (n&127)]
            = f2bf(acc[fm][fn][r]);
      }
    }
  }
}

// ---------------- MFMA GEMM: dbuf + global_load_lds, conflict-free LDS ------
// C[M,N] = sum_k A[m,k]*B[k,n]. A bf16 K-major, <=3 segments of 1024 cols.
// B is bf16 BT [N,K] row-major (K-major operand). Dual-problem via z_split.
// LDS: per 128x32 tile (8KB/buf), 8 blocks of 16 rows; slot l (16B) of block g
// holds [row = g*16 + (l&15)][k-oct = l>>4]. Staged by gload_lds16 with lane l
// fetching global [row=l&15][oct=l>>4]  ->  fragment read = ds_read_b128 at
// base + lane*16: consecutive lanes -> consecutive banks, ZERO conflicts.
// epi: 0 bf16 C[z*cp+m*ldc+n]*alpha | 1 bf16 head-merge | 2 fp32 +bias[n]
//      3 bf16 head-split | 4 fp32 head-merge
__global__ __launch_bounds__(256)
void gemm_kernel(const u16* __restrict__ A0, const u16* __restrict__ A1,
                 const u16* __restrict__ A2, const u16* __restrict__ A0b,
                 const u16* __restrict__ A1b,
                 const u16* __restrict__ B1, const u16* __restrict__ B2,
                 void* __restrict__ Cv, void* __restrict__ Cv2,
                 const float* __restrict__ bias,
                 int K1, int K2, int lda, int ldb1, int ldb2, int ldc,
                 long a_plane, long b_plane, long c_plane,
                 int epi1, int epi2, int z_split, float alpha)
{
  __shared__ __attribute__((aligned(16))) u16 sA[2][4096];
  __shared__ __attribute__((aligned(16))) u16 sB[2][4096];
  const int t = threadIdx.x;
  const int m0 = blockIdx.y*128, n0 = blockIdx.x*128;
  const int zz = blockIdx.z;
  const bool side = (zz >= z_split);
  const int z = side ? (zz - z_split) : zz;
  const u16* a0 = (side ? A0b : A0) + (size_t)z*a_plane;
  const u16* a1 = (side ? A1b : A1) + (size_t)z*a_plane;
  const u16* a2 = A2 + (size_t)z*a_plane;
  const u16* bB = (side ? B2 : B1) + (size_t)z*b_plane;
  void* Cp = side ? Cv2 : Cv;
  const int EPI = side ? epi2 : epi1;
  const int K   = side ? K2 : K1;
  const int ldb = side ? ldb2 : ldb1;

  const int wave = t>>6, lane = t&63;
  const int wm = (wave>>1)*64, wn = (wave&1)*64;
  const int lm = lane&15, q = lane>>4;

  const f32x4 zero4 = {0.f,0.f,0.f,0.f};
  f32x4 acc[4][4];
#pragma unroll
  for (int i=0;i<4;i++)
#pragma unroll
    for (int j=0;j<4;j++) acc[i][j] = zero4;

  const int arowblk = wave*32;       // this wave stages 16-row blocks arowblk, +16

  const int KT = K >> 5;

  auto issueA = [&](int kt, int buf){
    const int kg = kt<<5, seg = kg>>10, ka = kg&1023;
    const u16* Ap = (seg==0) ? a0 : (seg==1 ? a1 : a2);
#pragma unroll
    for (int rr=0; rr<2; ++rr){
      const int rb = arowblk + rr*16;
      gload_lds16(Ap + (size_t)(m0+rb+lm)*lda + (ka + q*8), &sA[buf][rb*32]);
    }
  };
  auto issueB = [&](int kt, int buf){
    const int kg = kt<<5;
#pragma unroll
    for (int rr=0; rr<2; ++rr){
      const int rb = arowblk + rr*16;
      gload_lds16(bB + (size_t)(n0+rb+lm)*ldb + (kg + q*8), &sB[buf][rb*32]);
    }
  };

  // prologue: stage tile 0 into buffer 0
  issueA(0, 0);
  issueB(0, 0);

  int cur = 0;
  for (int kt=0; kt<KT; ++kt){
    __syncthreads();                        // drains vmcnt: buf[cur] ready
    if (kt+1 < KT){
      issueA(kt+1, cur^1);                  // async into other buffer
      issueB(kt+1, cur^1);
    }
    bf16x8 af[4], bfr[4];
#pragma unroll
    for (int f=0; f<4; ++f){
      af[f]  = *(const bf16x8*)&sA[cur][((wm>>4)+f)*512 + lane*8];
      bfr[f] = *(const bf16x8*)&sB[cur][((wn>>4)+f)*512 + lane*8];
    }
#pragma unroll
    for (int fm=0; fm<4; ++fm)
#pragma unroll
      for (int fn=0; fn<4; ++fn)
        acc[fm][fn] = __builtin_amdgcn_mfma_f32_16x16x32_bf16(af[fm], bfr[fn], acc[fm][fn], 0, 0, 0);
    cur ^= 1;
  }

#pragma unroll
  for (int fm=0; fm<4; ++fm){
#pragma unroll
    for (int fn=0; fn<4; ++fn){
#pragma unroll
      for (int r=0; r<4; ++r){
        const int m = m0 + wm + fm*16 + q*4 + r;
        const int n = n0 + wn + fn*16 + lm;
        float val = acc[fm][fn][r] * alpha;
        if (EPI == 0){
          ((u16*)Cp)[(size_t)z*c_plane + (size_t)m*ldc + n] = f2bf(val);
        } else if (EPI == 1){
          ((u16*)Cp)[((size_t)(z>>3)*NSEQ + m)*DIM + (size_t)(z&7)*DHEAD + n] = f2bf(val);
        } else if (EPI == 2){
          ((float*)Cp)[(size_t)m*ldc + n] = val + bias[n];
        } else if (EPI == 3){
          ((u16*)Cp)[(size_t)(((m>>10)*HEADS + (n>>7))*NSEQ + (m&1023))*DHEAD + (n&127)] = f2bf(val);
        } else {
          ((float*)Cp)[((size_t)(z>>3)*NSEQ + m)*DIM + (size_t)(z&7)*DHEAD + n] = val;
        }
      }
    }
  }
}

// ------- split-K final projection: out_pre[4096,1024] @ WoT -> partials -----
// K=1024 split into 4 slices of 256. 1024 blocks, chunked XCD swizzle so the
// 8 x-siblings sharing an A-tile run on ONE XCD (A fetched once per slice,
// B L2-resident per XCD). Partials fp32 [4][4096][1024] (reuses sim region).
__global__ __launch_bounds__(256)
void gemm8_kernel(const u16* __restrict__ A, const u16* __restrict__ B,
                  float* __restrict__ P)
{
  __shared__ __attribute__((aligned(16))) u16 sA[2][4096];
  __shared__ __attribute__((aligned(16))) u16 sB[2][4096];
  const int t = threadIdx.x;
  const int bid = blockIdx.x;
  const int w = (bid & 7)*128 + (bid >> 3);
  const int x = w & 7;          // N tile (0..7)
  const int y = (w >> 3) & 31;  // M tile (0..31)
  const int s = w >> 8;         // K slice (0..3)
  const int m0 = y*128, n0 = x*128, k0 = s*256;

  const int wave = t>>6, lane = t&63;
  const int wm = (wave>>1)*64, wn = (wave&1)*64;
  const int lm = lane&15, q = lane>>4;

  const f32x4 zero4 = {0.f,0.f,0.f,0.f};
  f32x4 acc[4][4];
#pragma unroll
  for (int i=0;i<4;i++)
#pragma unroll
    for (int j=0;j<4;j++) acc[i][j] = zero4;

  const int arowblk = wave*32;

  auto issueA = [&](int kt, int buf){
    const int kg = k0 + (kt<<5);
#pragma unroll
    for (int rr=0; rr<2; ++rr){
      const int rb = arowblk + rr*16;
      gload_lds16(A + (size_t)(m0+rb+lm)*1024 + (kg + q*8), &sA[buf][rb*32]);
    }
  };
  auto issueB = [&](int kt, int buf){
    const int kg = k0 + (kt<<5);
#pragma unroll
    for (int rr=0; rr<2; ++rr){
      const int rb = arowblk + rr*16;
      gload_lds16(B + (size_t)(n0+rb+lm)*1024 + (kg + q*8), &sB[buf][rb*32]);
    }
  };

  issueA(0, 0); issueB(0, 0);

  int cur = 0;
  for (int kt=0; kt<8; ++kt){
    __syncthreads();
    if (kt+1 < 8){
      issueA(kt+1, cur^1);
      issueB(kt+1, cur^1);
    }
    bf16x8 af[4], bfr[4];
#pragma unroll
    for (int f=0; f<4; ++f){
      af[f]  = *(const bf16x8*)&sA[cur][((wm>>4)+f)*512 + lane*8];
      bfr[f] = *(const bf16x8*)&sB[cur][((wn>>4)+f)*512 + lane*8];
    }
#pragma unroll
    for (int fm=0; fm<4; ++fm)
#pragma unroll
      for (int fn=0; fn<4; ++fn)
        acc[fm][fn] = __builtin_amdgcn_mfma_f32_16x16x32_bf16(af[fm], bfr[fn], acc[fm][fn], 0, 0, 0);
    cur ^= 1;
  }

  float* Pp = P + (size_t)s*4194304;   // 4096*1024 per slice
#pragma unroll
  for (int fm=0; fm<4; ++fm){
#pragma unroll
    for (int fn=0; fn<4; ++fn){
#pragma unroll
      for (int r=0; r<4; ++r){
        const int m = m0 + wm + fm*16 + q*4 + r;
        const int n = n0 + wn + fn*16 + lm;
        Pp[(size_t)m*1024 + n] = acc[fm][fn][r];
      }
    }
  }
}

// ------- reduce 4 fp32 partial planes + bias -> out (fp32) ------------------
__global__ __launch_bounds__(256)
void red8_kernel(const float* __restrict__ P, const float* __restrict__ bias,
                 float* __restrict__ out)
{
  const int idx = blockIdx.x*256 + threadIdx.x;   // float4 index, 1M total
  const float4* P4 = (const float4*)P;
  float4 a = P4[idx];
  float4 b = P4[idx + 1048576];
  float4 c = P4[idx + 2097152];
  float4 d = P4[idx + 3145728];
  float4 bb = ((const float4*)bias)[idx & 255];
  float4 o;
  o.x = a.x + b.x + c.x + d.x + bb.x;
  o.y = a.y + b.y + c.y + d.y + bb.y;
  o.z = a.z + b.z + c.z + d.z + bb.z;
  o.w = a.w + b.w + c.w + d.w + bb.w;
  ((float4*)out)[idx] = o;
}

// ------- transpose both operands: [32][1024][128] -> [32][128][1024] --------
// grid (4,32,64): z<32 -> cond->condT plane z; z>=32 -> refv->refvT plane z-32
__global__ __launch_bounds__(256)
void transpose2_kernel(const u16* __restrict__ cond, const u16* __restrict__ refv,
                       u16* __restrict__ condT, u16* __restrict__ refvT)
{
  __shared__ u16 tile[32][33];
  const int zz = blockIdx.z;
  const u16* X = (zz < 32) ? cond : refv;
  u16* XT      = (zz < 32) ? condT : refvT;
  const int z = zz & 31;
  const int i0 = blockIdx.y*32, d0 = blockIdx.x*32;
  const int t = threadIdx.x;
  const int tc = t & 31, tr = t >> 5;
  const u16* Xp = X + (size_t)z*NSEQ*DHEAD;
#pragma unroll
  for (int p=0;p<4;p++){
    int i = tr + p*8;
    tile[i][tc] = Xp[(size_t)(i0+i)*DHEAD + d0 + tc];
  }
  __syncthreads();
  u16* Op = XT + (size_t)z*DHEAD*NSEQ;
#pragma unroll
  for (int p=0;p<4;p++){
    int d = tr + p*8;
    Op[(size_t)(d0+d)*NSEQ + i0 + tc] = tile[tc][d];
  }
}

// ---------------- softmax stats: row + col fused in one launch ---------------
// grid 8704: blocks [0,8192) row stats (4 rows/block, 1 wave each);
//            blocks [8192,8704) col stats (64 cols/block, 4 i-slices, 2-pass)
__global__ __launch_bounds__(256)
void stats_kernel(const u16* __restrict__ sim,
                  float* __restrict__ rmax, float* __restrict__ rrcp,
                  float* __restrict__ cmax, float* __restrict__ crcp)
{
  __shared__ float smx[4][64], ssm[4][64];
  if (blockIdx.x < 8192){
    const int wave = threadIdx.x >> 6, lane = threadIdx.x & 63;
    const int row = blockIdx.x*4 + wave;   // (b*8+h)*1024+i
    const u16* sr = sim + (size_t)row * NSEQ;
    float v[16]; float m = -1e30f;
#pragma unroll
    for (int c=0;c<16;c++){ v[c] = bf2f(sr[lane + c*64]); m = fmaxf(m, v[c]); }
#pragma unroll
    for (int off=32; off; off>>=1) m = fmaxf(m, __shfl_xor(m, off));
    float s = 0.f;
#pragma unroll
    for (int c=0;c<16;c++) s += __expf(v[c]-m);
#pragma unroll
    for (int off=32; off; off>>=1) s += __shfl_xor(s, off);
    if (lane == 0){ rmax[row] = m; rrcp[row] = 1.0f/s; }
  } else {
    const int t = threadIdx.x;
    const int jl = t & 63, slice = t >> 6;
    const int c = (blockIdx.x - 8192)*64 + jl;   // (b*8+h)*1024 + j
    const int bh = c >> 10, j = c & 1023;
    const u16* sp = sim + (size_t)bh*NSEQ*NSEQ + j + (size_t)(slice*256)*NSEQ;
    // pass 1: max only, 4 independent chains
    float m0=-1e30f, m1=-1e30f, m2=-1e30f, m3=-1e30f;
    for (int i=0;i<256;i+=4){
      m0 = fmaxf(m0, bf2f(sp[(size_t)(i  )*NSEQ]));
      m1 = fmaxf(m1, bf2f(sp[(size_t)(i+1)*NSEQ]));
      m2 = fmaxf(m2, bf2f(sp[(size_t)(i+2)*NSEQ]));
      m3 = fmaxf(m3, bf2f(sp[(size_t)(i+3)*NSEQ]));
    }
    smx[slice][jl] = fmaxf(fmaxf(m0,m1), fmaxf(m2,m3));
    __syncthreads();
    const float M = fmaxf(fmaxf(smx[0][jl], smx[1][jl]),
                          fmaxf(smx[2][jl], smx[3][jl]));
    // pass 2: sum of exp against final max (data L2-hot), 4 chains
    float s0=0.f, s1=0.f, s2=0.f, s3=0.f;
    for (int i=0;i<256;i+=4){
      s0 += __expf(bf2f(sp[(size_t)(i  )*NSEQ]) - M);
      s1 += __expf(bf2f(sp[(size_t)(i+1)*NSEQ]) - M);
      s2 += __expf(bf2f(sp[(size_t)(i+2)*NSEQ]) - M);
      s3 += __expf(bf2f(sp[(size_t)(i+3)*NSEQ]) - M);
    }
    ssm[slice][jl] = s0+s1+s2+s3;
    __syncthreads();
    if (slice == 0){
      float S = ssm[0][jl] + ssm[1][jl] + ssm[2][jl] + ssm[3][jl];
      cmax[c] = M; crcp[c] = 1.0f/S;
    }
  }
}

// ---------------- softmax + talking-heads mix ----------------
// IN-PLACE: am overwrites sim (per-thread read-before-write, same addresses).
// Also writes cmT[b,g,j,i] (transposed via LDS).
__global__ __launch_bounds__(256)
void mix_kernel(u16* simam,
                const float* __restrict__ rmax, const float* __restrict__ rrcp,
                const float* __restrict__ cmax, const float* __restrict__ crcp,
                const float* __restrict__ thw, const float* __restrict__ cthw,
                u16* __restrict__ cmT)
{
  __shared__ float s_th[64], s_cth[64];
  __shared__ u16 s_cm[8][32][33];
  const int t = threadIdx.x;
  if (t < 64){ s_th[t] = thw[t]; s_cth[t] = cthw[t]; }
  __syncthreads();
  const int b = blockIdx.z, i0 = blockIdx.y*32, j0 = blockIdx.x*32;
  const int tj = t & 31, ti = t >> 5;
  for (int p=0;p<4;p++){
    const int i = ti + p*8;
    float a[8], c[8];
#pragma unroll
    for (int h=0;h<8;h++){
      const int bh = b*8 + h;
      const float v = bf2f(simam[((size_t)bh*NSEQ + (i0+i))*NSEQ + j0 + tj]);
      a[h] = __expf(v - rmax[(size_t)bh*NSEQ + i0+i]) * rrcp[(size_t)bh*NSEQ + i0+i];
      c[h] = __expf(v - cmax[(size_t)bh*NSEQ + j0+tj]) * crcp[(size_t)bh*NSEQ + j0+tj];
    }
#pragma unroll
    for (int g=0;g<8;g++){
      float sa = 0.f, sc = 0.f;
#pragma unroll
      for (int h=0;h<8;h++){ sa += s_th[g*8+h]*a[h]; sc += s_cth[g*8+h]*c[h]; }
      simam[((size_t)(b*8+g)*NSEQ + (i0+i))*NSEQ + j0 + tj] = f2bf(sa);
      s_cm[g][i][tj] = f2bf(sc);
    }
  }
  __syncthreads();
#pragma unroll
  for (int g=0;g<8;g++){
#pragma unroll
    for (int p=0;p<4;p++){
      const int j = ti + p*8;
      cmT[((size_t)(b*8+g)*NSEQ + (j0+j))*NSEQ + i0 + tj] = s_cm[g][tj][j];
    }
  }
}

extern "C" void kernel_launch(void* const* d_in, const int* in_sizes, int n_in,
                              void* d_out, int out_size, void* d_ws, size_t ws_size,
                              hipStream_t stream)
{
  const float* x     = (const float*)d_in[0];
  const float* cinfo = (const float*)d_in[1];
  const float* ref   = (const float*)d_in[2];
  const float* ln_w  = (const float*)d_in[3];
  const float* ln_b  = (const float*)d_in[4];
  const float* cln_w = (const float*)d_in[5];
  const float* cln_b = (const float*)d_in[6];
  const float* Wk    = (const float*)d_in[7];
  const float* Wv    = (const float*)d_in[8];
  const float* Wo    = (const float*)d_in[9];
  const float* bo    = (const float*)d_in[10];
  const float* thw   = (const float*)d_in[11];
  const float* cthw  = (const float*)d_in[12];
  float* out = (float*)d_out;

  char* ws = (char*)d_ws;
  u16* xn    = (u16*)(ws + 0);          // 8 MB; reused as out_pre
  u16* cn    = (u16*)(ws + 8388608);    // 8 MB; reused for softmax stats
  u16* rn    = (u16*)(ws + 16777216);   // 8 MB
  u16* cond  = (u16*)(ws + 25165824);   // 8 MB  [b,h,i,d]
  u16* refv  = (u16*)(ws + 33554432);   // 8 MB  [b,h,j,d]
  u16* condT = (u16*)(ws + 41943040);   // 8 MB  [b,h,d,j]
  u16* refvT = (u16*)(ws + 50331648);   // 8 MB  [b,h,d,j]
  u16* sim   = (u16*)(ws + 58720256);   // 64 MB [b,h,i,j]; becomes am in-place;
                                        //        reused as fp32 partials for step 8
  u16* cmT   = (u16*)(ws + 125829120);  // 64 MB [b,g,j,i]
  u16* WkT   = (u16*)(ws + 192937984);  // 6 MB  [1024,3072] bf16
  u16* WvT   = (u16*)(ws + 199229440);  // 4 MB  [1024,2048] bf16
  u16* WoT   = (u16*)(ws + 203423744);  // 2 MB  [1024,1024] bf16
  float* rmax = (float*)(ws + 8388608);
  float* rrcp = (float*)(ws + 8388608 + 131072);
  float* cmax = (float*)(ws + 8388608 + 262144);
  float* crcp = (float*)(ws + 8388608 + 393216);
  u16* out_pre = (u16*)(ws + 0);

  // 1) LayerNorms (fp32 -> bf16), all three in one launch
  ln3_kernel<<<dim3(4096,3), 256, 0, stream>>>(x, ref, cinfo, ln_w, ln_b,
                                               cln_w, cln_b, xn, rn, cn);

  // 1b) weight convert+transpose fp32[K,N] -> bf16[N,K]
  wcvt_kernel<<<dim3(96,32,3), 256, 0, stream>>>(Wk, Wv, Wo, WkT, WvT, WoT);

  // 2) fused projections, 64x64-per-wave reg-blocked (no LDS, no barriers):
  //    z=0 -> [xn|cn|rn]@Wk -> cond; z=1 -> [xn|rn]@Wv -> refv
  gemm64_kernel<<<dim3(8,32,2), 256, 0, stream>>>(xn, cn, rn, WkT, WvT, cond, refv);

  // 3) transposed copies for the PV/context GEMM B-operands (one launch)
  transpose2_kernel<<<dim3(4,32,64), 256, 0, stream>>>(cond, refv, condT, refvT);

  // 4) sim = cond @ refv^T * scale  (per (b,h) plane)
  gemm_kernel<<<dim3(8,8,32), 256, 0, stream>>>(
      cond, cond, cond, cond, cond, refv, refv, sim, sim, nullptr,
      DHEAD, DHEAD, DHEAD, DHEAD, DHEAD, NSEQ,
      (long)NSEQ*DHEAD, (long)NSEQ*DHEAD, (long)NSEQ*NSEQ, 0, 0, 1000000, ATT_SCALE);

  // 5) softmax stats (row + col in one launch; col is 2-pass max/sum)
  stats_kernel<<<8704, 256, 0, stream>>>(sim, rmax, rrcp, cmax, crcp);

  // 6) both softmaxes + talking heads (am in-place over sim; cmT transposed)
  mix_kernel<<<dim3(32,32,4), 256, 0, stream>>>(sim, rmax, rrcp, cmax, crcp, thw, cthw, cmT);

  // 7) fused: z<32: am@refvT -> out_pre (bf16 head-merge); z>=32: cmT@condT -> ctx out (fp32)
  gemm_kernel<<<dim3(1,8,64), 256, 0, stream>>>(
      sim, sim, sim, cmT, cmT, refvT, condT, out_pre, out + (size_t)BATCH*NSEQ*DIM, nullptr,
      1024, 1024, NSEQ, NSEQ, NSEQ, 0,
      (long)NSEQ*NSEQ, (long)DHEAD*NSEQ, 0, 1, 4, 32, 1.0f);

  // 8) final projection, split-K=4 + chunked XCD swizzle: partials into sim
  //    region (dead after step 7), then deterministic reduce + bias.
  gemm8_kernel<<<1024, 256, 0, stream>>>(out_pre, WoT, (float*)sim);
  red8_kernel<<<4096, 256, 0, stream>>>((const float*)sim, bo, out);
}

// Round 5
// 467.893 us; speedup vs baseline: 1.1460x; 1.1460x over previous
//
#include <hip/hip_runtime.h>
#include <hip/hip_bf16.h>
#include <stdint.h>

typedef unsigned short u16;
typedef __attribute__((ext_vector_type(8))) short bf16x8;
typedef __attribute__((ext_vector_type(4))) float f32x4;

#define HEADS 8
#define DHEAD 128
#define NSEQ 1024
#define BATCH 4
#define DIM 1024
#define ATT_SCALE 0.088388347648318447f  // 1/sqrt(128)

static __device__ __forceinline__ float bf2f(u16 u){
  union { unsigned int i; float f; } c; c.i = ((unsigned int)u) << 16; return c.f;
}
static __device__ __forceinline__ u16 f2bf(float f){
  union { float f; unsigned int i; } c; c.f = f;
  unsigned int x = c.i;
  return (u16)((x + 0x7fffu + ((x >> 16) & 1u)) >> 16);
}

// async global->LDS, 16B per lane, dest = wave-uniform base + lane*16
static __device__ __forceinline__ void gload_lds16(const void* g, void* l){
  __builtin_amdgcn_global_load_lds((__attribute__((address_space(1))) void*)(g),
                                   (__attribute__((address_space(3))) void*)(l),
                                   16, 0, 0);
}

// ---------------- LayerNorm x3 fused: fp32 in, bf16 out ---------------------
// grid (4096, 3): y=0 x->xn (ln), y=1 ref->rn (ln), y=2 cinfo->cn (cln)
__global__ __launch_bounds__(256)
void ln3_kernel(const float* __restrict__ x, const float* __restrict__ ref,
                const float* __restrict__ cinfo,
                const float* __restrict__ ln_w, const float* __restrict__ ln_b,
                const float* __restrict__ cln_w, const float* __restrict__ cln_b,
                u16* __restrict__ xn, u16* __restrict__ rn, u16* __restrict__ cn)
{
  const int z = blockIdx.y;
  const float* src = (z==0) ? x : (z==1) ? ref : cinfo;
  const float* w   = (z==2) ? cln_w : ln_w;
  const float* b   = (z==2) ? cln_b : ln_b;
  u16* out         = (z==0) ? xn : (z==1) ? rn : cn;

  const int row = blockIdx.x;
  const int t = threadIdx.x;
  const float* xr = src + (size_t)row * DIM;
  float4 v4 = *(const float4*)(xr + t*4);
  float v[4] = {v4.x, v4.y, v4.z, v4.w};
  float s = v[0]+v[1]+v[2]+v[3];
  __shared__ float red[256];
  red[t] = s; __syncthreads();
  for (int o=128;o;o>>=1){ if (t<o) red[t]+=red[t+o]; __syncthreads(); }
  const float mean = red[0] * (1.0f/DIM);
  __syncthreads();
  s = 0.f;
#pragma unroll
  for (int i=0;i<4;i++){ float d = v[i]-mean; s += d*d; }
  red[t] = s; __syncthreads();
  for (int o=128;o;o>>=1){ if (t<o) red[t]+=red[t+o]; __syncthreads(); }
  const float rstd = rsqrtf(red[0]*(1.0f/DIM) + 1e-5f);
  float4 w4 = *(const float4*)(w + t*4);
  float4 b4 = *(const float4*)(b + t*4);
  float wv[4] = {w4.x, w4.y, w4.z, w4.w};
  float bv[4] = {b4.x, b4.y, b4.z, b4.w};
  union { uint2 u; u16 s[4]; } ov;
#pragma unroll
  for (int i=0;i<4;i++)
    ov.s[i] = f2bf((v[i]-mean)*rstd*wv[i] + bv[i]);
  *(uint2*)(out + (size_t)row*DIM + t*4) = ov.u;
}

// -------- weight convert+transpose: fp32 [K,1024] -> bf16 [1024,K] ----------
__global__ __launch_bounds__(256)
void wcvt_kernel(const float* __restrict__ Wk, const float* __restrict__ Wv,
                 const float* __restrict__ Wo,
                 u16* __restrict__ WkT, u16* __restrict__ WvT, u16* __restrict__ WoT)
{
  const int z = blockIdx.z;
  const int K = (z==0) ? 3072 : (z==1) ? 2048 : 1024;
  if ((int)blockIdx.x*32 >= K) return;
  const float* W = (z==0) ? Wk : (z==1) ? Wv : Wo;
  u16* WT = (z==0) ? WkT : (z==1) ? WvT : WoT;
  __shared__ float tile[32][33];
  const int k0 = blockIdx.x*32, n0 = blockIdx.y*32;
  const int t = threadIdx.x, tc = t&31, tr = t>>5;
#pragma unroll
  for (int p=0;p<4;p++)
    tile[tr+p*8][tc] = W[(size_t)(k0+tr+p*8)*DIM + n0+tc];
  __syncthreads();
#pragma unroll
  for (int p=0;p<4;p++)
    WT[(size_t)(n0+tr+p*8)*K + k0+tc] = f2bf(tile[tc][tr+p*8]);
}

// ---------------- MFMA GEMM: dbuf + global_load_lds, conflict-free LDS ------
// C[M,N] = sum_k A[m,k]*B[k,n]. A bf16 K-major, <=3 segments of 1024 cols.
// B is bf16 BT [N,K] row-major (K-major operand). Dual-problem via z_split.
// Template BK = K-tile depth (32 or 64). BK=64 stages two 32-k sub-tiles per
// buffer -> HALF the barriers per unit K (for grid-starved dispatches where
// blocks/CU is fixed at 2, barrier+drain latency is the dominant stall).
// LDS layout per 32-k sub-tile: 8 blocks of 16 rows; slot l (16B) of block g
// holds [row=g*16+(l&15)][k-oct=l>>4]. Staged by gload_lds16 with lane l
// fetching global [row=l&15][oct=l>>4]  ->  fragment read = ds_read_b128 at
// base + lane*16: consecutive lanes -> consecutive banks, ZERO conflicts.
// epi: 0 bf16 C[z*cp+m*ldc+n]*alpha | 1 bf16 head-merge | 2 fp32 +bias[n]
//      3 bf16 head-split | 4 fp32 head-merge
template<int BK>
__global__ __launch_bounds__(256)
void gemm_kernel(const u16* __restrict__ A0, const u16* __restrict__ A1,
                 const u16* __restrict__ A2, const u16* __restrict__ A0b,
                 const u16* __restrict__ A1b,
                 const u16* __restrict__ B1, const u16* __restrict__ B2,
                 void* __restrict__ Cv, void* __restrict__ Cv2,
                 const float* __restrict__ bias,
                 int K1, int K2, int lda, int ldb1, int ldb2, int ldc,
                 long a_plane, long b_plane, long c_plane,
                 int epi1, int epi2, int z_split, float alpha)
{
  constexpr int SUBS = BK/32;                       // 32-k sub-tiles per buffer
  __shared__ __attribute__((aligned(16))) u16 sA[2][SUBS*4096];
  __shared__ __attribute__((aligned(16))) u16 sB[2][SUBS*4096];
  const int t = threadIdx.x;
  const int m0 = blockIdx.y*128, n0 = blockIdx.x*128;
  const int zz = blockIdx.z;
  const bool side = (zz >= z_split);
  const int z = side ? (zz - z_split) : zz;
  const u16* a0 = (side ? A0b : A0) + (size_t)z*a_plane;
  const u16* a1 = (side ? A1b : A1) + (size_t)z*a_plane;
  const u16* a2 = A2 + (size_t)z*a_plane;
  const u16* bB = (side ? B2 : B1) + (size_t)z*b_plane;
  void* Cp = side ? Cv2 : Cv;
  const int EPI = side ? epi2 : epi1;
  const int K   = side ? K2 : K1;
  const int ldb = side ? ldb2 : ldb1;

  const int wave = t>>6, lane = t&63;
  const int wm = (wave>>1)*64, wn = (wave&1)*64;
  const int lm = lane&15, q = lane>>4;

  const f32x4 zero4 = {0.f,0.f,0.f,0.f};
  f32x4 acc[4][4];
#pragma unroll
  for (int i=0;i<4;i++)
#pragma unroll
    for (int j=0;j<4;j++) acc[i][j] = zero4;

  const int arowblk = wave*32;       // this wave stages 16-row blocks arowblk, +16

  const int KT = K / BK;

  auto issueA = [&](int kt, int buf){
    const int kg = kt*BK, seg = kg>>10, ka = kg&1023;  // BK-tile never crosses a 1024 seg
    const u16* Ap = (seg==0) ? a0 : (seg==1 ? a1 : a2);
#pragma unroll
    for (int sub=0; sub<SUBS; ++sub)
#pragma unroll
      for (int rr=0; rr<2; ++rr){
        const int rb = arowblk + rr*16;
        gload_lds16(Ap + (size_t)(m0+rb+lm)*lda + (ka + sub*32 + q*8),
                    &sA[buf][sub*4096 + rb*32]);
      }
  };
  auto issueB = [&](int kt, int buf){
    const int kg = kt*BK;
#pragma unroll
    for (int sub=0; sub<SUBS; ++sub)
#pragma unroll
      for (int rr=0; rr<2; ++rr){
        const int rb = arowblk + rr*16;
        gload_lds16(bB + (size_t)(n0+rb+lm)*ldb + (kg + sub*32 + q*8),
                    &sB[buf][sub*4096 + rb*32]);
      }
  };

  // prologue: stage tile 0 into buffer 0
  issueA(0, 0);
  issueB(0, 0);

  int cur = 0;
  for (int kt=0; kt<KT; ++kt){
    __syncthreads();                        // drains vmcnt: buf[cur] ready
    if (kt+1 < KT){
      issueA(kt+1, cur^1);                  // async into other buffer
      issueB(kt+1, cur^1);
    }
#pragma unroll
    for (int sub=0; sub<SUBS; ++sub){
      bf16x8 af[4], bfr[4];
#pragma unroll
      for (int f=0; f<4; ++f){
        af[f]  = *(const bf16x8*)&sA[cur][sub*4096 + ((wm>>4)+f)*512 + lane*8];
        bfr[f] = *(const bf16x8*)&sB[cur][sub*4096 + ((wn>>4)+f)*512 + lane*8];
      }
#pragma unroll
      for (int fm=0; fm<4; ++fm)
#pragma unroll
        for (int fn=0; fn<4; ++fn)
          acc[fm][fn] = __builtin_amdgcn_mfma_f32_16x16x32_bf16(af[fm], bfr[fn], acc[fm][fn], 0, 0, 0);
    }
    cur ^= 1;
  }

#pragma unroll
  for (int fm=0; fm<4; ++fm){
#pragma unroll
    for (int fn=0; fn<4; ++fn){
#pragma unroll
      for (int r=0; r<4; ++r){
        const int m = m0 + wm + fm*16 + q*4 + r;
        const int n = n0 + wn + fn*16 + lm;
        float val = acc[fm][fn][r] * alpha;
        if (EPI == 0){
          ((u16*)Cp)[(size_t)z*c_plane + (size_t)m*ldc + n] = f2bf(val);
        } else if (EPI == 1){
          ((u16*)Cp)[((size_t)(z>>3)*NSEQ + m)*DIM + (size_t)(z&7)*DHEAD + n] = f2bf(val);
        } else if (EPI == 2){
          ((float*)Cp)[(size_t)m*ldc + n] = val + bias[n];
        } else if (EPI == 3){
          ((u16*)Cp)[(size_t)(((m>>10)*HEADS + (n>>7))*NSEQ + (m&1023))*DHEAD + (n&127)] = f2bf(val);
        } else {
          ((float*)Cp)[((size_t)(z>>3)*NSEQ + m)*DIM + (size_t)(z&7)*DHEAD + n] = val;
        }
      }
    }
  }
}

// ------- split-K final projection: out_pre[4096,1024] @ WoT -> partials -----
// K=1024 split into 4 slices of 256. 1024 blocks, chunked XCD swizzle so the
// 8 x-siblings sharing an A-tile run on ONE XCD (A fetched once per slice,
// B L2-resident per XCD). Partials fp32 [4][4096][1024] (reuses sim region).
__global__ __launch_bounds__(256)
void gemm8_kernel(const u16* __restrict__ A, const u16* __restrict__ B,
                  float* __restrict__ P)
{
  __shared__ __attribute__((aligned(16))) u16 sA[2][4096];
  __shared__ __attribute__((aligned(16))) u16 sB[2][4096];
  const int t = threadIdx.x;
  const int bid = blockIdx.x;
  const int w = (bid & 7)*128 + (bid >> 3);
  const int x = w & 7;          // N tile (0..7)
  const int y = (w >> 3) & 31;  // M tile (0..31)
  const int s = w >> 8;         // K slice (0..3)
  const int m0 = y*128, n0 = x*128, k0 = s*256;

  const int wave = t>>6, lane = t&63;
  const int wm = (wave>>1)*64, wn = (wave&1)*64;
  const int lm = lane&15, q = lane>>4;

  const f32x4 zero4 = {0.f,0.f,0.f,0.f};
  f32x4 acc[4][4];
#pragma unroll
  for (int i=0;i<4;i++)
#pragma unroll
    for (int j=0;j<4;j++) acc[i][j] = zero4;

  const int arowblk = wave*32;

  auto issueA = [&](int kt, int buf){
    const int kg = k0 + (kt<<5);
#pragma unroll
    for (int rr=0; rr<2; ++rr){
      const int rb = arowblk + rr*16;
      gload_lds16(A + (size_t)(m0+rb+lm)*1024 + (kg + q*8), &sA[buf][rb*32]);
    }
  };
  auto issueB = [&](int kt, int buf){
    const int kg = k0 + (kt<<5);
#pragma unroll
    for (int rr=0; rr<2; ++rr){
      const int rb = arowblk + rr*16;
      gload_lds16(B + (size_t)(n0+rb+lm)*1024 + (kg + q*8), &sB[buf][rb*32]);
    }
  };

  issueA(0, 0); issueB(0, 0);

  int cur = 0;
  for (int kt=0; kt<8; ++kt){
    __syncthreads();
    if (kt+1 < 8){
      issueA(kt+1, cur^1);
      issueB(kt+1, cur^1);
    }
    bf16x8 af[4], bfr[4];
#pragma unroll
    for (int f=0; f<4; ++f){
      af[f]  = *(const bf16x8*)&sA[cur][((wm>>4)+f)*512 + lane*8];
      bfr[f] = *(const bf16x8*)&sB[cur][((wn>>4)+f)*512 + lane*8];
    }
#pragma unroll
    for (int fm=0; fm<4; ++fm)
#pragma unroll
      for (int fn=0; fn<4; ++fn)
        acc[fm][fn] = __builtin_amdgcn_mfma_f32_16x16x32_bf16(af[fm], bfr[fn], acc[fm][fn], 0, 0, 0);
    cur ^= 1;
  }

  float* Pp = P + (size_t)s*4194304;   // 4096*1024 per slice
#pragma unroll
  for (int fm=0; fm<4; ++fm){
#pragma unroll
    for (int fn=0; fn<4; ++fn){
#pragma unroll
      for (int r=0; r<4; ++r){
        const int m = m0 + wm + fm*16 + q*4 + r;
        const int n = n0 + wn + fn*16 + lm;
        Pp[(size_t)m*1024 + n] = acc[fm][fn][r];
      }
    }
  }
}

// ------- reduce 4 fp32 partial planes + bias -> out (fp32) ------------------
__global__ __launch_bounds__(256)
void red8_kernel(const float* __restrict__ P, const float* __restrict__ bias,
                 float* __restrict__ out)
{
  const int idx = blockIdx.x*256 + threadIdx.x;   // float4 index, 1M total
  const float4* P4 = (const float4*)P;
  float4 a = P4[idx];
  float4 b = P4[idx + 1048576];
  float4 c = P4[idx + 2097152];
  float4 d = P4[idx + 3145728];
  float4 bb = ((const float4*)bias)[idx & 255];
  float4 o;
  o.x = a.x + b.x + c.x + d.x + bb.x;
  o.y = a.y + b.y + c.y + d.y + bb.y;
  o.z = a.z + b.z + c.z + d.z + bb.z;
  o.w = a.w + b.w + c.w + d.w + bb.w;
  ((float4*)out)[idx] = o;
}

// ------- transpose both operands: [32][1024][128] -> [32][128][1024] --------
// grid (4,32,64): z<32 -> cond->condT plane z; z>=32 -> refv->refvT plane z-32
__global__ __launch_bounds__(256)
void transpose2_kernel(const u16* __restrict__ cond, const u16* __restrict__ refv,
                       u16* __restrict__ condT, u16* __restrict__ refvT)
{
  __shared__ u16 tile[32][33];
  const int zz = blockIdx.z;
  const u16* X = (zz < 32) ? cond : refv;
  u16* XT      = (zz < 32) ? condT : refvT;
  const int z = zz & 31;
  const int i0 = blockIdx.y*32, d0 = blockIdx.x*32;
  const int t = threadIdx.x;
  const int tc = t & 31, tr = t >> 5;
  const u16* Xp = X + (size_t)z*NSEQ*DHEAD;
#pragma unroll
  for (int p=0;p<4;p++){
    int i = tr + p*8;
    tile[i][tc] = Xp[(size_t)(i0+i)*DHEAD + d0 + tc];
  }
  __syncthreads();
  u16* Op = XT + (size_t)z*DHEAD*NSEQ;
#pragma unroll
  for (int p=0;p<4;p++){
    int d = tr + p*8;
    Op[(size_t)(d0+d)*NSEQ + i0 + tc] = tile[tc][d];
  }
}

// ---------------- softmax stats: row + col fused in one launch ---------------
// grid 8704: blocks [0,8192) row stats (4 rows/block, 1 wave each);
//            blocks [8192,8704) col stats (64 cols/block, 4 i-slices, 2-pass)
__global__ __launch_bounds__(256)
void stats_kernel(const u16* __restrict__ sim,
                  float* __restrict__ rmax, float* __restrict__ rrcp,
                  float* __restrict__ cmax, float* __restrict__ crcp)
{
  __shared__ float smx[4][64], ssm[4][64];
  if (blockIdx.x < 8192){
    const int wave = threadIdx.x >> 6, lane = threadIdx.x & 63;
    const int row = blockIdx.x*4 + wave;   // (b*8+h)*1024+i
    const u16* sr = sim + (size_t)row * NSEQ;
    float v[16]; float m = -1e30f;
#pragma unroll
    for (int c=0;c<16;c++){ v[c] = bf2f(sr[lane + c*64]); m = fmaxf(m, v[c]); }
#pragma unroll
    for (int off=32; off; off>>=1) m = fmaxf(m, __shfl_xor(m, off));
    float s = 0.f;
#pragma unroll
    for (int c=0;c<16;c++) s += __expf(v[c]-m);
#pragma unroll
    for (int off=32; off; off>>=1) s += __shfl_xor(s, off);
    if (lane == 0){ rmax[row] = m; rrcp[row] = 1.0f/s; }
  } else {
    const int t = threadIdx.x;
    const int jl = t & 63, slice = t >> 6;
    const int c = (blockIdx.x - 8192)*64 + jl;   // (b*8+h)*1024 + j
    const int bh = c >> 10, j = c & 1023;
    const u16* sp = sim + (size_t)bh*NSEQ*NSEQ + j + (size_t)(slice*256)*NSEQ;
    // pass 1: max only, 4 independent chains
    float m0=-1e30f, m1=-1e30f, m2=-1e30f, m3=-1e30f;
    for (int i=0;i<256;i+=4){
      m0 = fmaxf(m0, bf2f(sp[(size_t)(i  )*NSEQ]));
      m1 = fmaxf(m1, bf2f(sp[(size_t)(i+1)*NSEQ]));
      m2 = fmaxf(m2, bf2f(sp[(size_t)(i+2)*NSEQ]));
      m3 = fmaxf(m3, bf2f(sp[(size_t)(i+3)*NSEQ]));
    }
    smx[slice][jl] = fmaxf(fmaxf(m0,m1), fmaxf(m2,m3));
    __syncthreads();
    const float M = fmaxf(fmaxf(smx[0][jl], smx[1][jl]),
                          fmaxf(smx[2][jl], smx[3][jl]));
    // pass 2: sum of exp against final max (data L2-hot), 4 chains
    float s0=0.f, s1=0.f, s2=0.f, s3=0.f;
    for (int i=0;i<256;i+=4){
      s0 += __expf(bf2f(sp[(size_t)(i  )*NSEQ]) - M);
      s1 += __expf(bf2f(sp[(size_t)(i+1)*NSEQ]) - M);
      s2 += __expf(bf2f(sp[(size_t)(i+2)*NSEQ]) - M);
      s3 += __expf(bf2f(sp[(size_t)(i+3)*NSEQ]) - M);
    }
    ssm[slice][jl] = s0+s1+s2+s3;
    __syncthreads();
    if (slice == 0){
      float S = ssm[0][jl] + ssm[1][jl] + ssm[2][jl] + ssm[3][jl];
      cmax[c] = M; crcp[c] = 1.0f/S;
    }
  }
}

// ---------------- softmax + talking-heads mix ----------------
// IN-PLACE: am overwrites sim (per-thread read-before-write, same addresses).
// Also writes cmT[b,g,j,i] (transposed via LDS).
__global__ __launch_bounds__(256)
void mix_kernel(u16* simam,
                const float* __restrict__ rmax, const float* __restrict__ rrcp,
                const float* __restrict__ cmax, const float* __restrict__ crcp,
                const float* __restrict__ thw, const float* __restrict__ cthw,
                u16* __restrict__ cmT)
{
  __shared__ float s_th[64], s_cth[64];
  __shared__ u16 s_cm[8][32][33];
  const int t = threadIdx.x;
  if (t < 64){ s_th[t] = thw[t]; s_cth[t] = cthw[t]; }
  __syncthreads();
  const int b = blockIdx.z, i0 = blockIdx.y*32, j0 = blockIdx.x*32;
  const int tj = t & 31, ti = t >> 5;
  for (int p=0;p<4;p++){
    const int i = ti + p*8;
    float a[8], c[8];
#pragma unroll
    for (int h=0;h<8;h++){
      const int bh = b*8 + h;
      const float v = bf2f(simam[((size_t)bh*NSEQ + (i0+i))*NSEQ + j0 + tj]);
      a[h] = __expf(v - rmax[(size_t)bh*NSEQ + i0+i]) * rrcp[(size_t)bh*NSEQ + i0+i];
      c[h] = __expf(v - cmax[(size_t)bh*NSEQ + j0+tj]) * crcp[(size_t)bh*NSEQ + j0+tj];
    }
#pragma unroll
    for (int g=0;g<8;g++){
      float sa = 0.f, sc = 0.f;
#pragma unroll
      for (int h=0;h<8;h++){ sa += s_th[g*8+h]*a[h]; sc += s_cth[g*8+h]*c[h]; }
      simam[((size_t)(b*8+g)*NSEQ + (i0+i))*NSEQ + j0 + tj] = f2bf(sa);
      s_cm[g][i][tj] = f2bf(sc);
    }
  }
  __syncthreads();
#pragma unroll
  for (int g=0;g<8;g++){
#pragma unroll
    for (int p=0;p<4;p++){
      const int j = ti + p*8;
      cmT[((size_t)(b*8+g)*NSEQ + (j0+j))*NSEQ + i0 + tj] = s_cm[g][tj][j];
    }
  }
}

extern "C" void kernel_launch(void* const* d_in, const int* in_sizes, int n_in,
                              void* d_out, int out_size, void* d_ws, size_t ws_size,
                              hipStream_t stream)
{
  const float* x     = (const float*)d_in[0];
  const float* cinfo = (const float*)d_in[1];
  const float* ref   = (const float*)d_in[2];
  const float* ln_w  = (const float*)d_in[3];
  const float* ln_b  = (const float*)d_in[4];
  const float* cln_w = (const float*)d_in[5];
  const float* cln_b = (const float*)d_in[6];
  const float* Wk    = (const float*)d_in[7];
  const float* Wv    = (const float*)d_in[8];
  const float* Wo    = (const float*)d_in[9];
  const float* bo    = (const float*)d_in[10];
  const float* thw   = (const float*)d_in[11];
  const float* cthw  = (const float*)d_in[12];
  float* out = (float*)d_out;

  char* ws = (char*)d_ws;
  u16* xn    = (u16*)(ws + 0);          // 8 MB; reused as out_pre
  u16* cn    = (u16*)(ws + 8388608);    // 8 MB; reused for softmax stats
  u16* rn    = (u16*)(ws + 16777216);   // 8 MB
  u16* cond  = (u16*)(ws + 25165824);   // 8 MB  [b,h,i,d]
  u16* refv  = (u16*)(ws + 33554432);   // 8 MB  [b,h,j,d]
  u16* condT = (u16*)(ws + 41943040);   // 8 MB  [b,h,d,j]
  u16* refvT = (u16*)(ws + 50331648);   // 8 MB  [b,h,d,j]
  u16* sim   = (u16*)(ws + 58720256);   // 64 MB [b,h,i,j]; becomes am in-place;
                                        //        reused as fp32 partials for step 8
  u16* cmT   = (u16*)(ws + 125829120);  // 64 MB [b,g,j,i]
  u16* WkT   = (u16*)(ws + 192937984);  // 6 MB  [1024,3072] bf16
  u16* WvT   = (u16*)(ws + 199229440);  // 4 MB  [1024,2048] bf16
  u16* WoT   = (u16*)(ws + 203423744);  // 2 MB  [1024,1024] bf16
  float* rmax = (float*)(ws + 8388608);
  float* rrcp = (float*)(ws + 8388608 + 131072);
  float* cmax = (float*)(ws + 8388608 + 262144);
  float* crcp = (float*)(ws + 8388608 + 393216);
  u16* out_pre = (u16*)(ws + 0);

  // 1) LayerNorms (fp32 -> bf16), all three in one launch
  ln3_kernel<<<dim3(4096,3), 256, 0, stream>>>(x, ref, cinfo, ln_w, ln_b,
                                               cln_w, cln_b, xn, rn, cn);

  // 1b) weight convert+transpose fp32[K,N] -> bf16[N,K]
  wcvt_kernel<<<dim3(96,32,3), 256, 0, stream>>>(Wk, Wv, Wo, WkT, WvT, WoT);

  // 2) fused projections (BK=64: half the barriers; grid-starved at 2 blk/CU):
  //    z=0 -> [xn|cn|rn]@Wk -> cond; z=1 -> [xn|rn]@Wv -> refv
  gemm_kernel<64><<<dim3(8,32,2), 256, 0, stream>>>(
      xn, cn, rn, xn, rn, WkT, WvT, cond, refv, nullptr,
      3072, 2048, DIM, 3072, 2048, 0, 0, 0, 0, 3, 3, 1, 1.0f);

  // 3) transposed copies for the PV/context GEMM B-operands (one launch)
  transpose2_kernel<<<dim3(4,32,64), 256, 0, stream>>>(cond, refv, condT, refvT);

  // 4) sim = cond @ refv^T * scale  (per (b,h) plane; BK=32 keeps 4+ blk/CU)
  gemm_kernel<32><<<dim3(8,8,32), 256, 0, stream>>>(
      cond, cond, cond, cond, cond, refv, refv, sim, sim, nullptr,
      DHEAD, DHEAD, DHEAD, DHEAD, DHEAD, NSEQ,
      (long)NSEQ*DHEAD, (long)NSEQ*DHEAD, (long)NSEQ*NSEQ, 0, 0, 1000000, ATT_SCALE);

  // 5) softmax stats (row + col in one launch; col is 2-pass max/sum)
  stats_kernel<<<8704, 256, 0, stream>>>(sim, rmax, rrcp, cmax, crcp);

  // 6) both softmaxes + talking heads (am in-place over sim; cmT transposed)
  mix_kernel<<<dim3(32,32,4), 256, 0, stream>>>(sim, rmax, rrcp, cmax, crcp, thw, cthw, cmT);

  // 7) fused (BK=64): z<32: am@refvT -> out_pre (bf16 head-merge);
  //    z>=32: cmT@condT -> ctx out (fp32)
  gemm_kernel<64><<<dim3(1,8,64), 256, 0, stream>>>(
      sim, sim, sim, cmT, cmT, refvT, condT, out_pre, out + (size_t)BATCH*NSEQ*DIM, nullptr,
      1024, 1024, NSEQ, NSEQ, NSEQ, 0,
      (long)NSEQ*NSEQ, (long)DHEAD*NSEQ, 0, 1, 4, 32, 1.0f);

  // 8) final projection, split-K=4 + chunked XCD swizzle: partials into sim
  //    region (dead after step 7), then deterministic reduce + bias.
  gemm8_kernel<<<1024, 256, 0, stream>>>(out_pre, WoT, (float*)sim);
  red8_kernel<<<4096, 256, 0, stream>>>((const float*)sim, bo, out);
}